// Round 1
// baseline (49072.601 us; speedup 1.0000x reference)
//
#include <hip/hip_runtime.h>
#include <stdint.h>

// RGRNN: sequential sampled RNN.  B=64,T=512,I=H=1024.
// Persistent cooperative kernel, 256 WGs x 256 thr (1 WG/CU), bf16 MFMA
// 16x16x32, 2 grid barriers per step.  See round-0 notes.

#define Bdim 64
#define Tdim 512
#define Idim 1024
#define Hdim 1024
#define GRID 256
#define THREADS 256
#define FLAG_STRIDE 16  // ints -> 64B per flag line

// ws layout (bytes)
#define OFF_WCOMB 0u            // [1024][2048] bf16 : [w_ih | w_hh] rows
#define OFF_WGB   4194304u      // [2048][1024] bf16 : w_g rows
#define OFF_HBUF  8388608u      // [64][1024] bf16   : carried sample state
#define OFF_HRNN  8519680u      // [64][1024] bf16   : tanh output
#define OFF_PART  8650752u      // [64][64] f32      : log_prob partials [jb][b]
#define OFF_FLAGS 8667136u      // [256*16] int      : barrier flags

typedef __attribute__((ext_vector_type(8))) short short8;
typedef __attribute__((ext_vector_type(4))) float floatx4;

__device__ __forceinline__ unsigned short f2bf(float f) {
  union { float f; unsigned int u; } v; v.f = f;
  unsigned int r = v.u + 0x7FFFu + ((v.u >> 16) & 1u);  // RNE
  return (unsigned short)(r >> 16);
}

__device__ __forceinline__ void gbar(int* flags, int ph) {
  __threadfence();          // make this thread's global writes agent-visible
  __syncthreads();          // whole WG done (compiler drains vmcnt at barrier)
  if (threadIdx.x == 0)
    __hip_atomic_store(&flags[blockIdx.x * FLAG_STRIDE], ph,
                       __ATOMIC_RELEASE, __HIP_MEMORY_SCOPE_AGENT);
  // thread i waits on WG i's flag (GRID == THREADS)
  while (__hip_atomic_load(&flags[threadIdx.x * FLAG_STRIDE],
                           __ATOMIC_RELAXED, __HIP_MEMORY_SCOPE_AGENT) < ph) {
    __builtin_amdgcn_s_sleep(1);
  }
  __syncthreads();
  __threadfence();          // acquire side: invalidate stale caches
}

__global__ void rnn_init(const float* __restrict__ w_ih,
                         const float* __restrict__ w_hh,
                         const float* __restrict__ w_g,
                         unsigned char* __restrict__ ws) {
  unsigned short* wcomb = (unsigned short*)(ws + OFF_WCOMB);
  unsigned short* wgb   = (unsigned short*)(ws + OFF_WGB);
  unsigned short* hbuf  = (unsigned short*)(ws + OFF_HBUF);
  int* flags            = (int*)(ws + OFF_FLAGS);
  size_t idx = (size_t)blockIdx.x * blockDim.x + threadIdx.x;
  size_t stride = (size_t)gridDim.x * blockDim.x;
  for (size_t e = idx; e < 2097152u; e += stride) {
    int j = (int)(e >> 11), k = (int)(e & 2047);
    float v = (k < 1024) ? w_ih[j * 1024 + k] : w_hh[j * 1024 + (k - 1024)];
    wcomb[e] = f2bf(v);
  }
  for (size_t e = idx; e < 2097152u; e += stride) wgb[e] = f2bf(w_g[e]);
  for (size_t e = idx; e < 65536u; e += stride) hbuf[e] = 0;   // h0 = 0
  for (size_t e = idx; e < GRID * FLAG_STRIDE; e += stride) flags[e] = 0;
}

__global__ __launch_bounds__(THREADS, 1) void rnn_main(
    const float* __restrict__ x, const float* __restrict__ eps,
    const float* __restrict__ b_ih, const float* __restrict__ b_hh,
    const float* __restrict__ b_g,
    float* __restrict__ out, unsigned char* __restrict__ ws) {
  const unsigned short* wcomb = (const unsigned short*)(ws + OFF_WCOMB);
  const unsigned short* wgb   = (const unsigned short*)(ws + OFF_WGB);
  unsigned short* hbuf        = (unsigned short*)(ws + OFF_HBUF);
  unsigned short* hrnn        = (unsigned short*)(ws + OFF_HRNN);
  float* part                 = (float*)(ws + OFF_PART);
  int* flags                  = (int*)(ws + OFF_FLAGS);

  float* out_seq = out;
  float* out_p   = out + (size_t)Bdim * Tdim * Hdim;
  float* out_mu  = out_p + (size_t)Bdim * Tdim;
  float* out_std = out_mu + (size_t)Bdim * Tdim * Hdim;

  const int bb   = blockIdx.x >> 6;   // batch tile 0..3  (16 rows)
  const int jb   = blockIdx.x & 63;   // column tile 0..63 (16 cols)
  const int tid  = threadIdx.x;
  const int wave = tid >> 6;
  const int lane = tid & 63;
  const int m16  = lane & 15;
  const int quad = lane >> 4;

  const int b = bb * 16 + m16;        // A-fragment row (batch)
  const int j = jb * 16 + m16;        // B-fragment row (output column)

  __shared__ float red[4][16][17];

  const float NEG_HALF_H_LOG2PI = -940.9930580015848f;

  int ph = 0;
  for (int t = 0; t < Tdim; ++t) {
    // ---------------- phase A: h_rnn = tanh([x_t | h] * wcomb^T + bias) ----
    // piggyback: finalize log_prob of step t-1 (partials stable since last barrier)
    if (blockIdx.x < Bdim && wave == 0 && t > 0) {
      float v = part[lane * 64 + blockIdx.x];
      for (int off = 32; off; off >>= 1) v += __shfl_xor(v, off, 64);
      if (lane == 0) out_p[blockIdx.x * Tdim + (t - 1)] = v + NEG_HALF_H_LOG2PI;
    }

    floatx4 acc = {0.f, 0.f, 0.f, 0.f};
    if (wave < 2) {  // x half: k in [0,1024), fp32 load + cvt
      const float* xrow = x + ((size_t)b * Tdim + t) * Idim;
      const unsigned short* wrow = wcomb + (size_t)j * 2048;
      const int kbase = wave * 512 + quad * 8;
      #pragma unroll
      for (int i = 0; i < 16; ++i) {
        const int kA = kbase + 32 * i;
        const float4 x0 = *(const float4*)(xrow + kA);
        const float4 x1 = *(const float4*)(xrow + kA + 4);
        short8 a;
        a[0] = (short)f2bf(x0.x); a[1] = (short)f2bf(x0.y);
        a[2] = (short)f2bf(x0.z); a[3] = (short)f2bf(x0.w);
        a[4] = (short)f2bf(x1.x); a[5] = (short)f2bf(x1.y);
        a[6] = (short)f2bf(x1.z); a[7] = (short)f2bf(x1.w);
        const short8 w8 = *(const short8*)(wrow + kA);
        acc = __builtin_amdgcn_mfma_f32_16x16x32_bf16(a, w8, acc, 0, 0, 0);
      }
    } else {  // h half: k in [1024,2048), bf16 state
      const unsigned short* hrow = hbuf + b * 1024;
      const unsigned short* wrow = wcomb + (size_t)j * 2048 + 1024;
      const int kbase = (wave - 2) * 512 + quad * 8;
      #pragma unroll
      for (int i = 0; i < 16; ++i) {
        const int kA = kbase + 32 * i;
        const short8 a  = *(const short8*)(hrow + kA);
        const short8 w8 = *(const short8*)(wrow + kA);
        acc = __builtin_amdgcn_mfma_f32_16x16x32_bf16(a, w8, acc, 0, 0, 0);
      }
    }
    #pragma unroll
    for (int r = 0; r < 4; ++r) red[wave][quad * 4 + r][m16] = acc[r];
    __syncthreads();
    {
      const int row = tid >> 4, col = tid & 15;
      const int jj = jb * 16 + col;
      float s = red[0][row][col] + red[1][row][col] +
                red[2][row][col] + red[3][row][col] + b_ih[jj] + b_hh[jj];
      hrnn[(bb * 16 + row) * 1024 + jj] = f2bf(tanhf(s));
    }
    gbar(flags, ++ph);

    // ---------------- phase B: stats = h_rnn * w_g^T; sample; log_prob -----
    acc = (floatx4){0.f, 0.f, 0.f, 0.f};
    {
      const int tile = wave >> 1;                // 0 = std cols, 1 = mu cols
      const int n = (tile ? 1024 : 0) + jb * 16 + m16;
      const unsigned short* arow = hrnn + b * 1024;
      const unsigned short* brow = wgb + (size_t)n * 1024;
      const int kbase = (wave & 1) * 512 + quad * 8;
      #pragma unroll
      for (int i = 0; i < 16; ++i) {
        const int kA = kbase + 32 * i;
        const short8 a  = *(const short8*)(arow + kA);
        const short8 w8 = *(const short8*)(brow + kA);
        acc = __builtin_amdgcn_mfma_f32_16x16x32_bf16(a, w8, acc, 0, 0, 0);
      }
    }
    #pragma unroll
    for (int r = 0; r < 4; ++r) red[wave][quad * 4 + r][m16] = acc[r];
    __syncthreads();
    {
      const int row = tid >> 4, col = tid & 15;
      const int bi = bb * 16 + row;
      const int jj = jb * 16 + col;
      const float s_std = red[0][row][col] + red[1][row][col] + b_g[jj];
      const float s_mu  = red[2][row][col] + red[3][row][col] + b_g[1024 + jj];
      // softplus, stable
      const float stdv = fmaxf(s_std, 0.f) + __logf(1.f + __expf(-fabsf(s_std)));
      const size_t oidx = ((size_t)bi * Tdim + t) * Hdim + jj;
      const float e = eps[oidx];
      const float smp = s_mu + stdv * e;
      out_seq[oidx] = smp;
      out_mu[oidx]  = s_mu;
      out_std[oidx] = stdv;
      hbuf[bi * 1024 + jj] = f2bf(smp);
      float lp = -0.5f * e * e - __logf(stdv);   // z == eps exactly
      lp += __shfl_xor(lp, 1, 64);
      lp += __shfl_xor(lp, 2, 64);
      lp += __shfl_xor(lp, 4, 64);
      lp += __shfl_xor(lp, 8, 64);
      if (col == 0) part[jb * 64 + bi] = lp;
    }
    gbar(flags, ++ph);
  }

  // finalize log_prob for t = T-1
  if (blockIdx.x < Bdim && wave == 0) {
    float v = part[lane * 64 + blockIdx.x];
    for (int off = 32; off; off >>= 1) v += __shfl_xor(v, off, 64);
    if (lane == 0) out_p[blockIdx.x * Tdim + (Tdim - 1)] = v + NEG_HALF_H_LOG2PI;
  }
}

extern "C" void kernel_launch(void* const* d_in, const int* in_sizes, int n_in,
                              void* d_out, int out_size, void* d_ws, size_t ws_size,
                              hipStream_t stream) {
  const float* x    = (const float*)d_in[0];
  const float* eps  = (const float*)d_in[1];
  const float* w_ih = (const float*)d_in[2];
  const float* w_hh = (const float*)d_in[3];
  const float* b_ih = (const float*)d_in[4];
  const float* b_hh = (const float*)d_in[5];
  const float* w_g  = (const float*)d_in[6];
  const float* b_g  = (const float*)d_in[7];
  float* out = (float*)d_out;
  unsigned char* ws = (unsigned char*)d_ws;

  hipLaunchKernelGGL(rnn_init, dim3(2048), dim3(256), 0, stream,
                     w_ih, w_hh, w_g, ws);

  void* args[] = {(void*)&x, (void*)&eps, (void*)&b_ih, (void*)&b_hh,
                  (void*)&b_g, (void*)&out, (void*)&ws};
  hipLaunchCooperativeKernel((void*)rnn_main, dim3(GRID), dim3(THREADS),
                             args, 0, stream);
}